// Round 20
// baseline (206.455 us; speedup 1.0000x reference)
//
#include <hip/hip_runtime.h>
#include <hip/hip_bf16.h>

#define BGR 4096      // graphs per side
#define DIM 256
#define NG  8         // graphs per fused block (pipelined)
#define HS  257       // LDS row stride for rel_kernel (fp32)

// fused-kernel LDS map (43008 B, NO aliasing):
#define OFF_EB 0      // Ebf: 32 x 528B
#define OFF_YT 16896  // YT: 128 x 80B
#define OFF_H1 27136  // H1T: 64 x 72B
#define OFF_A2 31744  // A2:  32 x 272B
#define OFF_CW 40448  // counts: 2 x 320 u32

typedef __bf16 bf16x8 __attribute__((ext_vector_type(8)));
typedef __bf16 bf16x4 __attribute__((ext_vector_type(4)));
typedef float  f32x4  __attribute__((ext_vector_type(4)));

__device__ __forceinline__ unsigned short f2b(float f) {
  unsigned u = __builtin_bit_cast(unsigned, f);
  u = (u + 0x7FFFu + ((u >> 16) & 1u)) >> 16;   // RNE
  return (unsigned short)u;
}

__device__ __forceinline__ bf16x4 cvt4(f32x4 c) {
  bf16x4 r;
  r[0] = (__bf16)c[0]; r[1] = (__bf16)c[1]; r[2] = (__bf16)c[2]; r[3] = (__bf16)c[3];
  return r;
}

// LDS-only barrier: drain own ds ops, raw s_barrier, no vmcnt drain.
__device__ __forceinline__ void lds_barrier() {
  asm volatile("s_waitcnt lgkmcnt(0)" ::: "memory");
  __builtin_amdgcn_s_barrier();
  __builtin_amdgcn_sched_barrier(0);
}

// ---------------------------------------------------------------------------
// Weight prep: W1b = [WO1;WI1] bf16 [128 rows][256 k], W2b = [WO2|WI2] bf16
// [256 rows][128 k], b1 = bO1+bI1 (f32[64]), b2 = bO2+bI2 (f32[256]).
// ---------------------------------------------------------------------------
__global__ void wcvt_kernel(
    const float* __restrict__ WO1, const float* __restrict__ WI1,
    const float* __restrict__ WO2, const float* __restrict__ WI2,
    const float* __restrict__ bO1, const float* __restrict__ bI1,
    const float* __restrict__ bO2, const float* __restrict__ bI2,
    unsigned short* __restrict__ W1b, unsigned short* __restrict__ W2b,
    float* __restrict__ b1, float* __restrict__ b2)
{
  const int i = blockIdx.x * 256 + threadIdx.x;   // 0..32767
  { int j = i >> 8, k = i & 255;
    float v = (j < 64) ? WO1[j * 256 + k] : WI1[(j - 64) * 256 + k];
    W1b[i] = f2b(v); }
  { int j = i >> 7, k = i & 127;
    float v = (k < 64) ? WO2[j * 64 + k] : WI2[j * 64 + (k - 64)];
    W2b[i] = f2b(v); }
  if (i < 64)  b1[i] = bO1[i] + bI1[i];
  if (i < 256) b2[i] = bO2[i] + bI2[i];
}

// ---------------------------------------------------------------------------
// FUSED kernel, 3 barriers/graph, stage block OFF the critical path.
// Dataflow audit (producer -> consumer, separating barrier):
//   Ebf(g)  written at stage(g-1, after B2(g-1));  read P1(g)  -- B1(g)
//   YT(g)   written P1(g);                         read P2(g)  -- B2(g)
//   YT reuse: P2(g) reads before B4(g); P1(g+1) writes after B1(g+1)
//   H1T(g)  written P2(g), read P3(g): SAME WAVE rows (program order)
//   H1T reuse: P3(g) < B4(g) < B1(g+1) < P2(g+1)
//   A2(g)   written P3(g);                         read P4(g)  -- B4(g)
//   A2 reuse: P4(g) < B1(g+1) < B2(g+1) < P3(g+1)
//   cw[c](g) zeroed P1-region(g-1... pre-B2), counted stage(g-1), read P2(g):
//            count < B1(g) < B2(g) < P2(g)
// ---------------------------------------------------------------------------
__global__ __launch_bounds__(256)
__attribute__((amdgpu_waves_per_eu(1, 2)))
void fused_kernel(
    const float* __restrict__ subj, const float* __restrict__ obj,
    const int* __restrict__ ssrc, const int* __restrict__ sdst,
    const int* __restrict__ osrc, const int* __restrict__ odst,
    const unsigned short* __restrict__ W1b, const unsigned short* __restrict__ W2b,
    const float* __restrict__ b1, const float* __restrict__ b2,
    float* __restrict__ gout)
{
  __shared__ __align__(16) unsigned char S[43008];
  const int t = threadIdx.x, w = t >> 6, l = t & 63;
  const int ln16 = l & 15, kg = l >> 4;
  const int gid0 = blockIdx.x * NG;

  // ---- prologue ----
  float4 ev[8];
  int es = 0, ed = 0;
  {
    const int gid = gid0;
    const float* Eg = ((gid >> 12) ? obj : subj) + (size_t)(gid & (BGR - 1)) * 32 * DIM;
    #pragma unroll
    for (int i = 0; i < 8; i++)
      ev[i] = *(const float4*)(Eg + (w * 8 + i) * 256 + l * 4);
    if (t < 128) {
      es = (((gid >> 12) ? osrc : ssrc))[(gid & (BGR - 1)) * 128 + t] & 31;
      ed = (((gid >> 12) ? odst : sdst))[(gid & (BGR - 1)) * 128 + t] & 31;
    }
  }
  bf16x8 B0[8], B1[8];
  {
    const unsigned short* wb0 = W1b + ((2 * w) * 16 + ln16) * 256 + kg * 8;
    const unsigned short* wb1 = W1b + ((2 * w + 1) * 16 + ln16) * 256 + kg * 8;
    #pragma unroll
    for (int ks = 0; ks < 8; ks++) {
      B0[ks] = *(const bf16x8*)(wb0 + ks * 32);
      B1[ks] = *(const bf16x8*)(wb1 + ks * 32);
    }
  }
  bf16x8 AW[4][4];
  float4 b2v[4];
  #pragma unroll
  for (int q = 0; q < 4; q++) {
    const int mt = w * 4 + q;
    const unsigned short* wa = W2b + (mt * 16 + ln16) * 128 + kg * 8;
    #pragma unroll
    for (int ks = 0; ks < 4; ks++) AW[q][ks] = *(const bf16x8*)(wa + ks * 32);
    b2v[q] = *(const float4*)(b2 + mt * 16 + kg * 4);
  }
  const float b1j = b1[w * 16 + ln16];
  {
    unsigned* cw = (unsigned*)(S + OFF_CW);
    for (int i = t; i < 640; i += 256) cw[i] = 0;
  }
  __syncthreads();
  // count graph 0 into cw[0]; cvt graph 0 -> Ebf; load graph 1 into ev/es/ed
  if (t < 128) {
    unsigned* cw = (unsigned*)(S + OFF_CW);
    atomicAdd(&cw[ed * 8 + (es >> 2)], 1u << ((es & 3) * 8));
    atomicAdd(&cw[256 + ed], 1u);
    atomicAdd(&cw[288 + es], 1u);
  }
  #pragma unroll
  for (int i = 0; i < 8; i++) {
    f32x4 tmp = {ev[i].x, ev[i].y, ev[i].z, ev[i].w};
    *(bf16x4*)(S + OFF_EB + (w * 8 + i) * 528 + l * 8) = cvt4(tmp);
  }
  if (NG > 1) {
    const int gid = gid0 + 1;
    const float* Eg = ((gid >> 12) ? obj : subj) + (size_t)(gid & (BGR - 1)) * 32 * DIM;
    #pragma unroll
    for (int i = 0; i < 8; i++)
      ev[i] = *(const float4*)(Eg + (w * 8 + i) * 256 + l * 4);
    if (t < 128) {
      es = (((gid >> 12) ? osrc : ssrc))[(gid & (BGR - 1)) * 128 + t] & 31;
      ed = (((gid >> 12) ? odst : sdst))[(gid & (BGR - 1)) * 128 + t] & 31;
    }
  }

  for (int g = 0; g < NG; g++) {
    unsigned* cwc = (unsigned*)(S + OFF_CW + (g & 1) * 1280);
    unsigned* cwn = (unsigned*)(S + OFF_CW + ((g + 1) & 1) * 1280);

    lds_barrier();                                 // B1: Ebf(g), cw[g&1] ready

    // ---- P1: gemm0 -> YT[j][node]; also zero cw[nxt] (dead buffer) ----
    {
      f32x4 a00 = {0,0,0,0}, a01 = {0,0,0,0}, a10 = {0,0,0,0}, a11 = {0,0,0,0};
      const unsigned char* ea = S + OFF_EB + ln16 * 528 + kg * 16;
      #pragma unroll
      for (int ks = 0; ks < 8; ks++) {
        bf16x8 A0 = *(const bf16x8*)(ea + ks * 64);
        bf16x8 A1 = *(const bf16x8*)(ea + 16 * 528 + ks * 64);
        a00 = __builtin_amdgcn_mfma_f32_16x16x32_bf16(A0, B0[ks], a00, 0, 0, 0);
        a01 = __builtin_amdgcn_mfma_f32_16x16x32_bf16(A0, B1[ks], a01, 0, 0, 0);
        a10 = __builtin_amdgcn_mfma_f32_16x16x32_bf16(A1, B0[ks], a10, 0, 0, 0);
        a11 = __builtin_amdgcn_mfma_f32_16x16x32_bf16(A1, B1[ks], a11, 0, 0, 0);
      }
      *(bf16x4*)(S + OFF_YT + ((2 * w) * 16 + ln16) * 80 + (kg * 4) * 2)          = cvt4(a00);
      *(bf16x4*)(S + OFF_YT + ((2 * w + 1) * 16 + ln16) * 80 + (kg * 4) * 2)      = cvt4(a01);
      *(bf16x4*)(S + OFF_YT + ((2 * w) * 16 + ln16) * 80 + (16 + kg * 4) * 2)     = cvt4(a10);
      *(bf16x4*)(S + OFF_YT + ((2 * w + 1) * 16 + ln16) * 80 + (16 + kg * 4) * 2) = cvt4(a11);
      if (g + 1 < NG) for (int i = t; i < 320; i += 256) cwn[i] = 0;
    }
    lds_barrier();                                 // B2: YT ready; Ebf dead

    // ---- STAGE (off critical path): cvt(g+1)->Ebf, count(g+1), issue(g+2) ----
    if (g + 1 < NG) {
      #pragma unroll
      for (int i = 0; i < 8; i++) {
        f32x4 tmp = {ev[i].x, ev[i].y, ev[i].z, ev[i].w};
        *(bf16x4*)(S + OFF_EB + (w * 8 + i) * 528 + l * 8) = cvt4(tmp);
      }
      if (t < 128) {
        atomicAdd(&cwn[ed * 8 + (es >> 2)], 1u << ((es & 3) * 8));
        atomicAdd(&cwn[256 + ed], 1u);
        atomicAdd(&cwn[288 + es], 1u);
      }
      if (g + 2 < NG) {
        const int ngid = gid0 + g + 2, ngg = ngid & (BGR - 1);
        const float* Eg = ((ngid >> 12) ? obj : subj) + (size_t)ngg * 32 * DIM;
        #pragma unroll
        for (int i = 0; i < 8; i++)
          ev[i] = *(const float4*)(Eg + (w * 8 + i) * 256 + l * 4);
        if (t < 128) {
          es = (((ngid >> 12) ? osrc : ssrc))[ngg * 128 + t] & 31;
          ed = (((ngid >> 12) ? odst : sdst))[ngg * 128 + t] & 31;
        }
      }
    }

    // ---- P2: M fragments + step1 -> H1T (wave-private rows) ----
    bf16x8 m1f[2], m2f[2];
    #pragma unroll
    for (int hf = 0; hf < 2; hf++) {
      const int r = hf * 16 + ln16;
      const float fi = 1.0f / fmaxf((float)cwc[256 + r], 1.0f);
      const float fo = 1.0f / fmaxf((float)cwc[288 + r], 1.0f);
      const unsigned w0 = cwc[r * 8 + kg * 2], w1 = cwc[r * 8 + kg * 2 + 1];
      bf16x8 a, b;
      #pragma unroll
      for (int q = 0; q < 4; q++) {
        a[q]     = (__bf16)((float)((w0 >> (q * 8)) & 255u) * fi);
        a[4 + q] = (__bf16)((float)((w1 >> (q * 8)) & 255u) * fi);
      }
      #pragma unroll
      for (int q = 0; q < 8; q++) {
        const unsigned wq = cwc[(kg * 8 + q) * 8 + (r >> 2)];
        b[q] = (__bf16)((float)((wq >> ((r & 3) * 8)) & 255u) * fo);
      }
      m1f[hf] = a; m2f[hf] = b;
    }
    {
      bf16x8 Byo = *(const bf16x8*)(S + OFF_YT + (w * 16 + ln16) * 80 + kg * 16);
      bf16x8 Byi = *(const bf16x8*)(S + OFF_YT + (64 + w * 16 + ln16) * 80 + kg * 16);
      #pragma unroll
      for (int mt = 0; mt < 2; mt++) {
        f32x4 z = {0.f, 0.f, 0.f, 0.f};
        f32x4 c = __builtin_amdgcn_mfma_f32_16x16x32_bf16(m1f[mt], Byo, z, 0, 0, 0);
        c = __builtin_amdgcn_mfma_f32_16x16x32_bf16(m2f[mt], Byi, c, 0, 0, 0);
        f32x4 hv = { fmaxf(c[0] + b1j, 0.f), fmaxf(c[1] + b1j, 0.f),
                     fmaxf(c[2] + b1j, 0.f), fmaxf(c[3] + b1j, 0.f) };
        *(bf16x4*)(S + OFF_H1 + (w * 16 + ln16) * 72 + (mt * 16 + kg * 4) * 2) = cvt4(hv);
      }
    }
    // no barrier: P3 reads only this wave's H1T rows (program order)

    // ---- P3: step2 -> A2 ----
    {
      bf16x8 Af = *(const bf16x8*)(S + OFF_H1 + (w * 16 + ln16) * 72 + kg * 16);
      #pragma unroll
      for (int hf = 0; hf < 2; hf++)
        #pragma unroll
        for (int ntd = 0; ntd < 2; ntd++) {
          f32x4 z = {0.f, 0.f, 0.f, 0.f};
          f32x4 c = __builtin_amdgcn_mfma_f32_16x16x32_bf16(
              Af, hf ? m2f[ntd] : m1f[ntd], z, 0, 0, 0);
          *(bf16x4*)(S + OFF_A2 + (ntd * 16 + ln16) * 272 + hf * 128 + w * 32 + kg * 8) = cvt4(c);
        }
    }
    lds_barrier();                                 // B4: A2 ready

    // ---- P4: step3 (register W2) + fused mean readout ----
    {
      bf16x8 BF[2][4];
      #pragma unroll
      for (int ntd = 0; ntd < 2; ntd++)
        #pragma unroll
        for (int ks = 0; ks < 4; ks++)
          BF[ntd][ks] = *(const bf16x8*)(S + OFF_A2 + (ntd * 16 + ln16) * 272 + ks * 64 + kg * 16);
      #pragma unroll
      for (int q = 0; q < 4; q++) {
        const int mt = w * 4 + q;
        f32x4 a0 = {0.f, 0.f, 0.f, 0.f}, a1 = {0.f, 0.f, 0.f, 0.f};
        #pragma unroll
        for (int ks = 0; ks < 4; ks++) {
          a0 = __builtin_amdgcn_mfma_f32_16x16x32_bf16(AW[q][ks], BF[0][ks], a0, 0, 0, 0);
          a1 = __builtin_amdgcn_mfma_f32_16x16x32_bf16(AW[q][ks], BF[1][ks], a1, 0, 0, 0);
        }
        float v0 = fmaxf(a0[0] + b2v[q].x, 0.f) + fmaxf(a1[0] + b2v[q].x, 0.f);
        float v1 = fmaxf(a0[1] + b2v[q].y, 0.f) + fmaxf(a1[1] + b2v[q].y, 0.f);
        float v2 = fmaxf(a0[2] + b2v[q].z, 0.f) + fmaxf(a1[2] + b2v[q].z, 0.f);
        float v3 = fmaxf(a0[3] + b2v[q].w, 0.f) + fmaxf(a1[3] + b2v[q].w, 0.f);
        #pragma unroll
        for (int d = 1; d < 16; d <<= 1) {
          v0 += __shfl_xor(v0, d); v1 += __shfl_xor(v1, d);
          v2 += __shfl_xor(v2, d); v3 += __shfl_xor(v3, d);
        }
        if (ln16 == 0) {
          float4 o = { v0 * 0.03125f, v1 * 0.03125f, v2 * 0.03125f, v3 * 0.03125f };
          *(float4*)(gout + (size_t)(gid0 + g) * DIM + mt * 16 + kg * 4) = o;
        }
      }
    }
  }
}

// ---------------------------------------------------------------------------
// r_embs = relu(rel @ relW.T + relb). 16 rows per block. (fp32 VALU)
// ---------------------------------------------------------------------------
__global__ __launch_bounds__(256, 4) void rel_kernel(
    const float* __restrict__ rel, const float* __restrict__ relW,
    const float* __restrict__ relb, float* __restrict__ r_out)
{
  __shared__ float srel[16 * HS];
  const int t = threadIdx.x;
  const int b0 = blockIdx.x << 4;
  #pragma unroll
  for (int i = 0; i < 4; i++) {
    int f = (i << 8) + t;
    int r = f >> 6, k4 = f & 63;
    float4 x = *(const float4*)(rel + (size_t)(b0 + r) * DIM + (k4 << 2));
    float* d = &srel[r * HS + (k4 << 2)];
    d[0] = x.x; d[1] = x.y; d[2] = x.z; d[3] = x.w;
  }
  __syncthreads();
  const int r = t & 15, jg = t >> 4;
  const float* pa = &srel[r * HS];
  const float* w = relW + (size_t)(jg * 16) * DIM;
  float acc[16];
  #pragma unroll
  for (int jj = 0; jj < 16; jj++) acc[jj] = 0.f;
  for (int k0 = 0; k0 < DIM; k0 += 16) {
    float a[16];
    #pragma unroll
    for (int u = 0; u < 16; u++) a[u] = pa[k0 + u];
    #pragma unroll
    for (int jj = 0; jj < 16; jj++) {
      const float* wr = w + jj * DIM + k0;
      #pragma unroll
      for (int u = 0; u < 16; u += 4) {
        float4 wv = *(const float4*)(wr + u);
        acc[jj] += a[u]*wv.x + a[u+1]*wv.y + a[u+2]*wv.z + a[u+3]*wv.w;
      }
    }
  }
  float* outp = r_out + (size_t)(b0 + r) * DIM + jg * 16;
  #pragma unroll
  for (int jj = 0; jj < 16; jj++) outp[jj] = fmaxf(acc[jj] + relb[jg * 16 + jj], 0.f);
}

// ---------------------------------------------------------------------------
// Distances: pos = ||h+r-t||, neg = ||h[ch]+r-t[ct]||. One wave per triple.
// ---------------------------------------------------------------------------
__global__ __launch_bounds__(256) void dist_kernel(
    const float* __restrict__ hemb, const float* __restrict__ temb,
    const float* __restrict__ remb, const int* __restrict__ chx,
    const int* __restrict__ ctx, float* __restrict__ out)
{
  const int t = threadIdx.x;
  const int w = t >> 6, l = t & 63;
  const int b = (blockIdx.x << 2) + w;
  float4 h4 = *(const float4*)(hemb + (size_t)b * DIM + (l << 2));
  float4 r4 = *(const float4*)(remb + (size_t)b * DIM + (l << 2));
  float4 t4 = *(const float4*)(temb + (size_t)b * DIM + (l << 2));
  int hb = chx[b], tb = ctx[b];
  float4 hn = *(const float4*)(hemb + (size_t)hb * DIM + (l << 2));
  float4 tn = *(const float4*)(temb + (size_t)tb * DIM + (l << 2));
  float x0 = h4.x + r4.x - t4.x, x1 = h4.y + r4.y - t4.y;
  float x2 = h4.z + r4.z - t4.z, x3 = h4.w + r4.w - t4.w;
  float dp = x0*x0 + x1*x1 + x2*x2 + x3*x3;
  float y0 = hn.x + r4.x - tn.x, y1 = hn.y + r4.y - tn.y;
  float y2 = hn.z + r4.z - tn.z, y3 = hn.w + r4.w - tn.w;
  float dn = y0*y0 + y1*y1 + y2*y2 + y3*y3;
  #pragma unroll
  for (int off = 32; off >= 1; off >>= 1) {
    dp += __shfl_down(dp, off);
    dn += __shfl_down(dn, off);
  }
  if (l == 0) {
    out[b] = sqrtf(dp);
    out[BGR + b] = sqrtf(dn);
  }
}

extern "C" void kernel_launch(void* const* d_in, const int* in_sizes, int n_in,
                              void* d_out, int out_size, void* d_ws, size_t ws_size,
                              hipStream_t stream) {
  const float* subj_embs = (const float*)d_in[0];
  const float* obj_embs  = (const float*)d_in[1];
  const float* rel_tok   = (const float*)d_in[2];
  const int* subj_src = (const int*)d_in[3];
  const int* subj_dst = (const int*)d_in[4];
  const int* obj_src  = (const int*)d_in[5];
  const int* obj_dst  = (const int*)d_in[6];
  // d_in[7] = node_graph_ids (implicit by construction)
  const int* chx = (const int*)d_in[8];
  const int* ctx = (const int*)d_in[9];
  const float* WO1 = (const float*)d_in[10];
  const float* bO1 = (const float*)d_in[11];
  const float* WI1 = (const float*)d_in[12];
  const float* bI1 = (const float*)d_in[13];
  const float* WO2 = (const float*)d_in[14];
  const float* bO2 = (const float*)d_in[15];
  const float* WI2 = (const float*)d_in[16];
  const float* bI2 = (const float*)d_in[17];
  const float* relW = (const float*)d_in[18];
  const float* relb = (const float*)d_in[19];

  float* g_embs = (float*)d_ws;                           // [8192,256] f32 = 8 MB
  float* r_embs = g_embs + (size_t)2 * BGR * DIM;         // [4096,256] f32 = 4 MB
  unsigned short* W1b = (unsigned short*)((char*)d_ws + 12582912);  // 64 KB
  unsigned short* W2b = W1b + 32768;                                // 64 KB
  float* b1 = (float*)((char*)d_ws + 12713984);                     // 256 B
  float* b2 = b1 + 64;                                              // 1 KB
  float* out = (float*)d_out;                             // [8192]: pos | neg

  wcvt_kernel<<<128, 256, 0, stream>>>(WO1, WI1, WO2, WI2, bO1, bI1, bO2, bI2,
                                       W1b, W2b, b1, b2);
  fused_kernel<<<8192 / NG, 256, 0, stream>>>(
      subj_embs, obj_embs, subj_src, subj_dst, obj_src, obj_dst,
      W1b, W2b, b1, b2, g_embs);
  rel_kernel<<<BGR / 16, 256, 0, stream>>>(rel_tok, relW, relb, r_embs);
  dist_kernel<<<BGR / 4, 256, 0, stream>>>(
      g_embs, g_embs + (size_t)BGR * DIM, r_embs, chx, ctx, out);
}

// Round 21
// 182.187 us; speedup vs baseline: 1.1332x; 1.1332x over previous
//
#include <hip/hip_runtime.h>
#include <hip/hip_bf16.h>

#define BGR 4096      // graphs per side
#define DIM 256
#define NG  16        // graphs per fused block
#define NFUSED 512    // fused blocks; blocks [NFUSED, NFUSED+256) do rel
#define HS  257       // LDS row stride for rel role (fp32)

// fused-role LDS map (43008 B, no aliasing):
#define OFF_EB 0      // Ebf: 32 x 528B
#define OFF_YT 16896  // YT: 128 x 80B
#define OFF_H1 27136  // H1T: 64 x 72B
#define OFF_A2 31744  // A2:  32 x 272B
#define OFF_CW 40448  // counts: 2 x 320 u32

typedef __bf16 bf16x8 __attribute__((ext_vector_type(8)));
typedef __bf16 bf16x4 __attribute__((ext_vector_type(4)));
typedef float  f32x4  __attribute__((ext_vector_type(4)));

__device__ __forceinline__ bf16x8 cvt8(float4 a, float4 b) {
  bf16x8 r;
  r[0] = (__bf16)a.x; r[1] = (__bf16)a.y; r[2] = (__bf16)a.z; r[3] = (__bf16)a.w;
  r[4] = (__bf16)b.x; r[5] = (__bf16)b.y; r[6] = (__bf16)b.z; r[7] = (__bf16)b.w;
  return r;
}
__device__ __forceinline__ bf16x4 cvt4(f32x4 c) {
  bf16x4 r;
  r[0] = (__bf16)c[0]; r[1] = (__bf16)c[1]; r[2] = (__bf16)c[2]; r[3] = (__bf16)c[3];
  return r;
}

// LDS-only barrier: drain own ds ops, raw s_barrier, no vmcnt drain.
__device__ __forceinline__ void lds_barrier() {
  asm volatile("s_waitcnt lgkmcnt(0)" ::: "memory");
  __builtin_amdgcn_s_barrier();
  __builtin_amdgcn_sched_barrier(0);
}

// ---------------------------------------------------------------------------
// MEGA kernel: blocks < NFUSED run the fused CompGCN path (R20 body; weights
// converted from fp32 in the prologue -> wcvt kernel eliminated); blocks
// [NFUSED, NFUSED+256) run the rel GEMM (fp32 VALU) in fused's idle CU
// capacity (fused runs at ~11% occupancy -> rel is effectively free).
// ---------------------------------------------------------------------------
__global__ __launch_bounds__(256)
__attribute__((amdgpu_waves_per_eu(1, 2)))
void mega_kernel(
    const float* __restrict__ subj, const float* __restrict__ obj,
    const int* __restrict__ ssrc, const int* __restrict__ sdst,
    const int* __restrict__ osrc, const int* __restrict__ odst,
    const float* __restrict__ WO1, const float* __restrict__ WI1,
    const float* __restrict__ WO2, const float* __restrict__ WI2,
    const float* __restrict__ bO1, const float* __restrict__ bI1,
    const float* __restrict__ bO2, const float* __restrict__ bI2,
    const float* __restrict__ rel, const float* __restrict__ relW,
    const float* __restrict__ relb,
    float* __restrict__ gout, float* __restrict__ r_out)
{
  __shared__ __align__(16) unsigned char S[43008];
  const int t = threadIdx.x;

  if (blockIdx.x >= NFUSED) {
    // ================= rel role: r_embs = relu(rel @ relW^T + relb) ========
    float* srel = (float*)S;
    const int b0 = (blockIdx.x - NFUSED) << 4;
    #pragma unroll
    for (int i = 0; i < 4; i++) {
      int f = (i << 8) + t;
      int r = f >> 6, k4 = f & 63;
      float4 x = *(const float4*)(rel + (size_t)(b0 + r) * DIM + (k4 << 2));
      float* d = &srel[r * HS + (k4 << 2)];
      d[0] = x.x; d[1] = x.y; d[2] = x.z; d[3] = x.w;
    }
    __syncthreads();
    const int r = t & 15, jg = t >> 4;
    const float* pa = &srel[r * HS];
    const float* wr0 = relW + (size_t)(jg * 16) * DIM;
    float acc[16];
    #pragma unroll
    for (int jj = 0; jj < 16; jj++) acc[jj] = 0.f;
    for (int k0 = 0; k0 < DIM; k0 += 16) {
      float a[16];
      #pragma unroll
      for (int u = 0; u < 16; u++) a[u] = pa[k0 + u];
      #pragma unroll
      for (int jj = 0; jj < 16; jj++) {
        const float* wrr = wr0 + jj * DIM + k0;
        #pragma unroll
        for (int u = 0; u < 16; u += 4) {
          float4 wv = *(const float4*)(wrr + u);
          acc[jj] += a[u]*wv.x + a[u+1]*wv.y + a[u+2]*wv.z + a[u+3]*wv.w;
        }
      }
    }
    float* outp = r_out + (size_t)(b0 + r) * DIM + jg * 16;
    #pragma unroll
    for (int jj = 0; jj < 16; jj++)
      outp[jj] = fmaxf(acc[jj] + relb[jg * 16 + jj], 0.f);
    return;
  }

  // ================= fused role (R20 body, fp32-sourced weights) ===========
  const int w = t >> 6, l = t & 63;
  const int ln16 = l & 15, kg = l >> 4;
  const int gid0 = blockIdx.x * NG;

  // ---- prologue: graph-0 loads ----
  float4 ev[8];
  int es = 0, ed = 0;
  {
    const int gid = gid0;
    const float* Eg = ((gid >> 12) ? obj : subj) + (size_t)(gid & (BGR - 1)) * 32 * DIM;
    #pragma unroll
    for (int i = 0; i < 8; i++)
      ev[i] = *(const float4*)(Eg + (w * 8 + i) * 256 + l * 4);
    if (t < 128) {
      es = (((gid >> 12) ? osrc : ssrc))[(gid & (BGR - 1)) * 128 + t] & 31;
      ed = (((gid >> 12) ? odst : sdst))[(gid & (BGR - 1)) * 128 + t] & 31;
    }
  }
  // ---- W1cat fragments from fp32 (rows j0 = 2w*16+ln16, j1 = j0+16) ----
  bf16x8 B0[8], B1[8];
  {
    const int j0 = (2 * w) * 16 + ln16, j1 = (2 * w + 1) * 16 + ln16;
    const float* s0 = (j0 < 64) ? (WO1 + (size_t)j0 * 256) : (WI1 + (size_t)(j0 - 64) * 256);
    const float* s1 = (j1 < 64) ? (WO1 + (size_t)j1 * 256) : (WI1 + (size_t)(j1 - 64) * 256);
    #pragma unroll
    for (int ks = 0; ks < 8; ks++) {
      const int k = ks * 32 + kg * 8;
      B0[ks] = cvt8(*(const float4*)(s0 + k), *(const float4*)(s0 + k + 4));
      B1[ks] = cvt8(*(const float4*)(s1 + k), *(const float4*)(s1 + k + 4));
    }
  }
  // ---- W2cat fragments from fp32 (rows mt*16+ln16; k<64 WO2, else WI2) ----
  bf16x8 AW[4][4];
  float4 b2v[4];
  #pragma unroll
  for (int q = 0; q < 4; q++) {
    const int row = (w * 4 + q) * 16 + ln16;
    const float* o2 = WO2 + (size_t)row * 64;
    const float* i2 = WI2 + (size_t)row * 64;
    #pragma unroll
    for (int ks = 0; ks < 4; ks++) {
      const int k = ks * 32 + kg * 8;          // 0..127
      const float* sp = (k < 64) ? (o2 + k) : (i2 + (k - 64));
      AW[q][ks] = cvt8(*(const float4*)(sp), *(const float4*)(sp + 4));
    }
    const int jb = (w * 4 + q) * 16 + kg * 4;
    float4 bo = *(const float4*)(bO2 + jb);
    float4 bi = *(const float4*)(bI2 + jb);
    b2v[q] = make_float4(bo.x + bi.x, bo.y + bi.y, bo.z + bi.z, bo.w + bi.w);
  }
  const float b1j = bO1[w * 16 + ln16] + bI1[w * 16 + ln16];
  {
    unsigned* cw = (unsigned*)(S + OFF_CW);
    for (int i = t; i < 640; i += 256) cw[i] = 0;
  }
  __syncthreads();
  if (t < 128) {
    unsigned* cw = (unsigned*)(S + OFF_CW);
    atomicAdd(&cw[ed * 8 + (es >> 2)], 1u << ((es & 3) * 8));
    atomicAdd(&cw[256 + ed], 1u);
    atomicAdd(&cw[288 + es], 1u);
  }
  #pragma unroll
  for (int i = 0; i < 8; i++) {
    f32x4 tmp = {ev[i].x, ev[i].y, ev[i].z, ev[i].w};
    *(bf16x4*)(S + OFF_EB + (w * 8 + i) * 528 + l * 8) = cvt4(tmp);
  }
  if (NG > 1) {
    const int gid = gid0 + 1;
    const float* Eg = ((gid >> 12) ? obj : subj) + (size_t)(gid & (BGR - 1)) * 32 * DIM;
    #pragma unroll
    for (int i = 0; i < 8; i++)
      ev[i] = *(const float4*)(Eg + (w * 8 + i) * 256 + l * 4);
    if (t < 128) {
      es = (((gid >> 12) ? osrc : ssrc))[(gid & (BGR - 1)) * 128 + t] & 31;
      ed = (((gid >> 12) ? odst : sdst))[(gid & (BGR - 1)) * 128 + t] & 31;
    }
  }

  for (int g = 0; g < NG; g++) {
    unsigned* cwc = (unsigned*)(S + OFF_CW + (g & 1) * 1280);
    unsigned* cwn = (unsigned*)(S + OFF_CW + ((g + 1) & 1) * 1280);

    lds_barrier();                                 // B1: Ebf(g), cw[g&1] ready

    // ---- P1: gemm0 -> YT; zero cw[nxt] ----
    {
      f32x4 a00 = {0,0,0,0}, a01 = {0,0,0,0}, a10 = {0,0,0,0}, a11 = {0,0,0,0};
      const unsigned char* ea = S + OFF_EB + ln16 * 528 + kg * 16;
      #pragma unroll
      for (int ks = 0; ks < 8; ks++) {
        bf16x8 A0 = *(const bf16x8*)(ea + ks * 64);
        bf16x8 A1 = *(const bf16x8*)(ea + 16 * 528 + ks * 64);
        a00 = __builtin_amdgcn_mfma_f32_16x16x32_bf16(A0, B0[ks], a00, 0, 0, 0);
        a01 = __builtin_amdgcn_mfma_f32_16x16x32_bf16(A0, B1[ks], a01, 0, 0, 0);
        a10 = __builtin_amdgcn_mfma_f32_16x16x32_bf16(A1, B0[ks], a10, 0, 0, 0);
        a11 = __builtin_amdgcn_mfma_f32_16x16x32_bf16(A1, B1[ks], a11, 0, 0, 0);
      }
      *(bf16x4*)(S + OFF_YT + ((2 * w) * 16 + ln16) * 80 + (kg * 4) * 2)          = cvt4(a00);
      *(bf16x4*)(S + OFF_YT + ((2 * w + 1) * 16 + ln16) * 80 + (kg * 4) * 2)      = cvt4(a01);
      *(bf16x4*)(S + OFF_YT + ((2 * w) * 16 + ln16) * 80 + (16 + kg * 4) * 2)     = cvt4(a10);
      *(bf16x4*)(S + OFF_YT + ((2 * w + 1) * 16 + ln16) * 80 + (16 + kg * 4) * 2) = cvt4(a11);
      if (g + 1 < NG) for (int i = t; i < 320; i += 256) cwn[i] = 0;
    }
    lds_barrier();                                 // B2: YT ready; Ebf dead

    // ---- STAGE (off critical path): cvt(g+1), count(g+1), issue(g+2) ----
    if (g + 1 < NG) {
      #pragma unroll
      for (int i = 0; i < 8; i++) {
        f32x4 tmp = {ev[i].x, ev[i].y, ev[i].z, ev[i].w};
        *(bf16x4*)(S + OFF_EB + (w * 8 + i) * 528 + l * 8) = cvt4(tmp);
      }
      if (t < 128) {
        atomicAdd(&cwn[ed * 8 + (es >> 2)], 1u << ((es & 3) * 8));
        atomicAdd(&cwn[256 + ed], 1u);
        atomicAdd(&cwn[288 + es], 1u);
      }
      if (g + 2 < NG) {
        const int ngid = gid0 + g + 2, ngg = ngid & (BGR - 1);
        const float* Eg = ((ngid >> 12) ? obj : subj) + (size_t)ngg * 32 * DIM;
        #pragma unroll
        for (int i = 0; i < 8; i++)
          ev[i] = *(const float4*)(Eg + (w * 8 + i) * 256 + l * 4);
        if (t < 128) {
          es = (((ngid >> 12) ? osrc : ssrc))[ngg * 128 + t] & 31;
          ed = (((ngid >> 12) ? odst : sdst))[ngg * 128 + t] & 31;
        }
      }
    }

    // ---- P2: M fragments + step1 -> H1T ----
    bf16x8 m1f[2], m2f[2];
    #pragma unroll
    for (int hf = 0; hf < 2; hf++) {
      const int r = hf * 16 + ln16;
      const float fi = 1.0f / fmaxf((float)cwc[256 + r], 1.0f);
      const float fo = 1.0f / fmaxf((float)cwc[288 + r], 1.0f);
      const unsigned w0 = cwc[r * 8 + kg * 2], w1 = cwc[r * 8 + kg * 2 + 1];
      bf16x8 a, b;
      #pragma unroll
      for (int q = 0; q < 4; q++) {
        a[q]     = (__bf16)((float)((w0 >> (q * 8)) & 255u) * fi);
        a[4 + q] = (__bf16)((float)((w1 >> (q * 8)) & 255u) * fi);
      }
      #pragma unroll
      for (int q = 0; q < 8; q++) {
        const unsigned wq = cwc[(kg * 8 + q) * 8 + (r >> 2)];
        b[q] = (__bf16)((float)((wq >> ((r & 3) * 8)) & 255u) * fo);
      }
      m1f[hf] = a; m2f[hf] = b;
    }
    {
      bf16x8 Byo = *(const bf16x8*)(S + OFF_YT + (w * 16 + ln16) * 80 + kg * 16);
      bf16x8 Byi = *(const bf16x8*)(S + OFF_YT + (64 + w * 16 + ln16) * 80 + kg * 16);
      #pragma unroll
      for (int mt = 0; mt < 2; mt++) {
        f32x4 z = {0.f, 0.f, 0.f, 0.f};
        f32x4 c = __builtin_amdgcn_mfma_f32_16x16x32_bf16(m1f[mt], Byo, z, 0, 0, 0);
        c = __builtin_amdgcn_mfma_f32_16x16x32_bf16(m2f[mt], Byi, c, 0, 0, 0);
        f32x4 hv = { fmaxf(c[0] + b1j, 0.f), fmaxf(c[1] + b1j, 0.f),
                     fmaxf(c[2] + b1j, 0.f), fmaxf(c[3] + b1j, 0.f) };
        *(bf16x4*)(S + OFF_H1 + (w * 16 + ln16) * 72 + (mt * 16 + kg * 4) * 2) = cvt4(hv);
      }
    }
    // no barrier: P3 reads only this wave's H1T rows (program order)

    // ---- P3: step2 -> A2 ----
    {
      bf16x8 Af = *(const bf16x8*)(S + OFF_H1 + (w * 16 + ln16) * 72 + kg * 16);
      #pragma unroll
      for (int hf = 0; hf < 2; hf++)
        #pragma unroll
        for (int ntd = 0; ntd < 2; ntd++) {
          f32x4 z = {0.f, 0.f, 0.f, 0.f};
          f32x4 c = __builtin_amdgcn_mfma_f32_16x16x32_bf16(
              Af, hf ? m2f[ntd] : m1f[ntd], z, 0, 0, 0);
          *(bf16x4*)(S + OFF_A2 + (ntd * 16 + ln16) * 272 + hf * 128 + w * 32 + kg * 8) = cvt4(c);
        }
    }
    lds_barrier();                                 // B4: A2 ready

    // ---- P4: step3 (register W2) + fused mean readout ----
    {
      bf16x8 BF[2][4];
      #pragma unroll
      for (int ntd = 0; ntd < 2; ntd++)
        #pragma unroll
        for (int ks = 0; ks < 4; ks++)
          BF[ntd][ks] = *(const bf16x8*)(S + OFF_A2 + (ntd * 16 + ln16) * 272 + ks * 64 + kg * 16);
      #pragma unroll
      for (int q = 0; q < 4; q++) {
        const int mt = w * 4 + q;
        f32x4 a0 = {0.f, 0.f, 0.f, 0.f}, a1 = {0.f, 0.f, 0.f, 0.f};
        #pragma unroll
        for (int ks = 0; ks < 4; ks++) {
          a0 = __builtin_amdgcn_mfma_f32_16x16x32_bf16(AW[q][ks], BF[0][ks], a0, 0, 0, 0);
          a1 = __builtin_amdgcn_mfma_f32_16x16x32_bf16(AW[q][ks], BF[1][ks], a1, 0, 0, 0);
        }
        float v0 = fmaxf(a0[0] + b2v[q].x, 0.f) + fmaxf(a1[0] + b2v[q].x, 0.f);
        float v1 = fmaxf(a0[1] + b2v[q].y, 0.f) + fmaxf(a1[1] + b2v[q].y, 0.f);
        float v2 = fmaxf(a0[2] + b2v[q].z, 0.f) + fmaxf(a1[2] + b2v[q].z, 0.f);
        float v3 = fmaxf(a0[3] + b2v[q].w, 0.f) + fmaxf(a1[3] + b2v[q].w, 0.f);
        #pragma unroll
        for (int d = 1; d < 16; d <<= 1) {
          v0 += __shfl_xor(v0, d); v1 += __shfl_xor(v1, d);
          v2 += __shfl_xor(v2, d); v3 += __shfl_xor(v3, d);
        }
        if (ln16 == 0) {
          float4 o = { v0 * 0.03125f, v1 * 0.03125f, v2 * 0.03125f, v3 * 0.03125f };
          *(float4*)(gout + (size_t)(gid0 + g) * DIM + mt * 16 + kg * 4) = o;
        }
      }
    }
  }
}

// ---------------------------------------------------------------------------
// Distances: pos = ||h+r-t||, neg = ||h[ch]+r-t[ct]||. One wave per triple.
// ---------------------------------------------------------------------------
__global__ __launch_bounds__(256) void dist_kernel(
    const float* __restrict__ hemb, const float* __restrict__ temb,
    const float* __restrict__ remb, const int* __restrict__ chx,
    const int* __restrict__ ctx, float* __restrict__ out)
{
  const int t = threadIdx.x;
  const int w = t >> 6, l = t & 63;
  const int b = (blockIdx.x << 2) + w;
  float4 h4 = *(const float4*)(hemb + (size_t)b * DIM + (l << 2));
  float4 r4 = *(const float4*)(remb + (size_t)b * DIM + (l << 2));
  float4 t4 = *(const float4*)(temb + (size_t)b * DIM + (l << 2));
  int hb = chx[b], tb = ctx[b];
  float4 hn = *(const float4*)(hemb + (size_t)hb * DIM + (l << 2));
  float4 tn = *(const float4*)(temb + (size_t)tb * DIM + (l << 2));
  float x0 = h4.x + r4.x - t4.x, x1 = h4.y + r4.y - t4.y;
  float x2 = h4.z + r4.z - t4.z, x3 = h4.w + r4.w - t4.w;
  float dp = x0*x0 + x1*x1 + x2*x2 + x3*x3;
  float y0 = hn.x + r4.x - tn.x, y1 = hn.y + r4.y - tn.y;
  float y2 = hn.z + r4.z - tn.z, y3 = hn.w + r4.w - tn.w;
  float dn = y0*y0 + y1*y1 + y2*y2 + y3*y3;
  #pragma unroll
  for (int off = 32; off >= 1; off >>= 1) {
    dp += __shfl_down(dp, off);
    dn += __shfl_down(dn, off);
  }
  if (l == 0) {
    out[b] = sqrtf(dp);
    out[BGR + b] = sqrtf(dn);
  }
}

extern "C" void kernel_launch(void* const* d_in, const int* in_sizes, int n_in,
                              void* d_out, int out_size, void* d_ws, size_t ws_size,
                              hipStream_t stream) {
  const float* subj_embs = (const float*)d_in[0];
  const float* obj_embs  = (const float*)d_in[1];
  const float* rel_tok   = (const float*)d_in[2];
  const int* subj_src = (const int*)d_in[3];
  const int* subj_dst = (const int*)d_in[4];
  const int* obj_src  = (const int*)d_in[5];
  const int* obj_dst  = (const int*)d_in[6];
  // d_in[7] = node_graph_ids (implicit by construction)
  const int* chx = (const int*)d_in[8];
  const int* ctx = (const int*)d_in[9];
  const float* WO1 = (const float*)d_in[10];
  const float* bO1 = (const float*)d_in[11];
  const float* WI1 = (const float*)d_in[12];
  const float* bI1 = (const float*)d_in[13];
  const float* WO2 = (const float*)d_in[14];
  const float* bO2 = (const float*)d_in[15];
  const float* WI2 = (const float*)d_in[16];
  const float* bI2 = (const float*)d_in[17];
  const float* relW = (const float*)d_in[18];
  const float* relb = (const float*)d_in[19];

  float* g_embs = (float*)d_ws;                           // [8192,256] f32 = 8 MB
  float* r_embs = g_embs + (size_t)2 * BGR * DIM;         // [4096,256] f32 = 4 MB
  float* out = (float*)d_out;                             // [8192]: pos | neg

  mega_kernel<<<NFUSED + 256, 256, 0, stream>>>(
      subj_embs, obj_embs, subj_src, subj_dst, obj_src, obj_dst,
      WO1, WI1, WO2, WI2, bO1, bI1, bO2, bI2,
      rel_tok, relW, relb, g_embs, r_embs);
  dist_kernel<<<BGR / 4, 256, 0, stream>>>(
      g_embs, g_embs + (size_t)BGR * DIM, r_embs, chx, ctx, out);
}

// Round 22
// 178.542 us; speedup vs baseline: 1.1563x; 1.0204x over previous
//
#include <hip/hip_runtime.h>
#include <hip/hip_bf16.h>

#define BGR 4096      // graphs per side
#define DIM 256
#define NG  16        // graphs per fused block
#define NFUSED 512    // fused blocks; blocks [NFUSED, NFUSED+256) do rel
#define HS  257       // LDS row stride for rel role (fp32)

// fused-role LDS map (43008 B, no aliasing):
#define OFF_EB 0      // Ebf: 32 x 528B
#define OFF_YT 16896  // YT: 128 x 80B
#define OFF_H1 27136  // H1T: 64 x 72B
#define OFF_A2 31744  // A2:  32 x 272B
#define OFF_CW 40448  // counts: 2 x 320 u32

typedef __bf16 bf16x8 __attribute__((ext_vector_type(8)));
typedef __bf16 bf16x4 __attribute__((ext_vector_type(4)));
typedef float  f32x4  __attribute__((ext_vector_type(4)));

__device__ __forceinline__ unsigned short f2b(float f) {
  unsigned u = __builtin_bit_cast(unsigned, f);
  u = (u + 0x7FFFu + ((u >> 16) & 1u)) >> 16;   // RNE
  return (unsigned short)u;
}

__device__ __forceinline__ bf16x4 cvt4(f32x4 c) {
  bf16x4 r;
  r[0] = (__bf16)c[0]; r[1] = (__bf16)c[1]; r[2] = (__bf16)c[2]; r[3] = (__bf16)c[3];
  return r;
}

// LDS-only barrier: drain own ds ops, raw s_barrier, no vmcnt drain.
__device__ __forceinline__ void lds_barrier() {
  asm volatile("s_waitcnt lgkmcnt(0)" ::: "memory");
  __builtin_amdgcn_s_barrier();
  __builtin_amdgcn_sched_barrier(0);
}

// ---------------------------------------------------------------------------
// Weight prep: W1b = [WO1;WI1] bf16 [128 rows][256 k], W2b = [WO2|WI2] bf16
// [256 rows][128 k], b1 = bO1+bI1 (f32[64]), b2 = bO2+bI2 (f32[256]).
// Tiny (~2-3us) but keeps mega's fused-role prologue to pure fragment loads
// (R21's in-prologue fp32 conversion pushed VGPR 144->192 and cost ~8us).
// ---------------------------------------------------------------------------
__global__ void wcvt_kernel(
    const float* __restrict__ WO1, const float* __restrict__ WI1,
    const float* __restrict__ WO2, const float* __restrict__ WI2,
    const float* __restrict__ bO1, const float* __restrict__ bI1,
    const float* __restrict__ bO2, const float* __restrict__ bI2,
    unsigned short* __restrict__ W1b, unsigned short* __restrict__ W2b,
    float* __restrict__ b1, float* __restrict__ b2)
{
  const int i = blockIdx.x * 256 + threadIdx.x;   // 0..32767
  { int j = i >> 8, k = i & 255;
    float v = (j < 64) ? WO1[j * 256 + k] : WI1[(j - 64) * 256 + k];
    W1b[i] = f2b(v); }
  { int j = i >> 7, k = i & 127;
    float v = (k < 64) ? WO2[j * 64 + k] : WI2[j * 64 + (k - 64)];
    W2b[i] = f2b(v); }
  if (i < 64)  b1[i] = bO1[i] + bI1[i];
  if (i < 256) b2[i] = bO2[i] + bI2[i];
}

// ---------------------------------------------------------------------------
// MEGA kernel: blocks < NFUSED run the fused CompGCN path (R20 body with
// pre-converted bf16 weights); blocks [NFUSED, NFUSED+256) run the rel GEMM
// in fused's idle CU capacity.
// ---------------------------------------------------------------------------
__global__ __launch_bounds__(256)
__attribute__((amdgpu_waves_per_eu(1, 2)))
void mega_kernel(
    const float* __restrict__ subj, const float* __restrict__ obj,
    const int* __restrict__ ssrc, const int* __restrict__ sdst,
    const int* __restrict__ osrc, const int* __restrict__ odst,
    const unsigned short* __restrict__ W1b, const unsigned short* __restrict__ W2b,
    const float* __restrict__ b1, const float* __restrict__ b2,
    const float* __restrict__ rel, const float* __restrict__ relW,
    const float* __restrict__ relb,
    float* __restrict__ gout, float* __restrict__ r_out)
{
  __shared__ __align__(16) unsigned char S[43008];
  const int t = threadIdx.x;

  if (blockIdx.x >= NFUSED) {
    // ================= rel role: r_embs = relu(rel @ relW^T + relb) ========
    float* srel = (float*)S;
    const int b0 = (blockIdx.x - NFUSED) << 4;
    #pragma unroll
    for (int i = 0; i < 4; i++) {
      int f = (i << 8) + t;
      int r = f >> 6, k4 = f & 63;
      float4 x = *(const float4*)(rel + (size_t)(b0 + r) * DIM + (k4 << 2));
      float* d = &srel[r * HS + (k4 << 2)];
      d[0] = x.x; d[1] = x.y; d[2] = x.z; d[3] = x.w;
    }
    __syncthreads();
    const int r = t & 15, jg = t >> 4;
    const float* pa = &srel[r * HS];
    const float* wr0 = relW + (size_t)(jg * 16) * DIM;
    float acc[16];
    #pragma unroll
    for (int jj = 0; jj < 16; jj++) acc[jj] = 0.f;
    for (int k0 = 0; k0 < DIM; k0 += 16) {
      float a[16];
      #pragma unroll
      for (int u = 0; u < 16; u++) a[u] = pa[k0 + u];
      #pragma unroll
      for (int jj = 0; jj < 16; jj++) {
        const float* wrr = wr0 + jj * DIM + k0;
        #pragma unroll
        for (int u = 0; u < 16; u += 4) {
          float4 wv = *(const float4*)(wrr + u);
          acc[jj] += a[u]*wv.x + a[u+1]*wv.y + a[u+2]*wv.z + a[u+3]*wv.w;
        }
      }
    }
    float* outp = r_out + (size_t)(b0 + r) * DIM + jg * 16;
    #pragma unroll
    for (int jj = 0; jj < 16; jj++)
      outp[jj] = fmaxf(acc[jj] + relb[jg * 16 + jj], 0.f);
    return;
  }

  // ================= fused role (R20 body, bf16 weights) ===================
  const int w = t >> 6, l = t & 63;
  const int ln16 = l & 15, kg = l >> 4;
  const int gid0 = blockIdx.x * NG;

  float4 ev[8];
  int es = 0, ed = 0;
  {
    const int gid = gid0;
    const float* Eg = ((gid >> 12) ? obj : subj) + (size_t)(gid & (BGR - 1)) * 32 * DIM;
    #pragma unroll
    for (int i = 0; i < 8; i++)
      ev[i] = *(const float4*)(Eg + (w * 8 + i) * 256 + l * 4);
    if (t < 128) {
      es = (((gid >> 12) ? osrc : ssrc))[(gid & (BGR - 1)) * 128 + t] & 31;
      ed = (((gid >> 12) ? odst : sdst))[(gid & (BGR - 1)) * 128 + t] & 31;
    }
  }
  bf16x8 B0[8], B1[8];
  {
    const unsigned short* wb0 = W1b + ((2 * w) * 16 + ln16) * 256 + kg * 8;
    const unsigned short* wb1 = W1b + ((2 * w + 1) * 16 + ln16) * 256 + kg * 8;
    #pragma unroll
    for (int ks = 0; ks < 8; ks++) {
      B0[ks] = *(const bf16x8*)(wb0 + ks * 32);
      B1[ks] = *(const bf16x8*)(wb1 + ks * 32);
    }
  }
  bf16x8 AW[4][4];
  float4 b2v[4];
  #pragma unroll
  for (int q = 0; q < 4; q++) {
    const int mt = w * 4 + q;
    const unsigned short* wa = W2b + (mt * 16 + ln16) * 128 + kg * 8;
    #pragma unroll
    for (int ks = 0; ks < 4; ks++) AW[q][ks] = *(const bf16x8*)(wa + ks * 32);
    b2v[q] = *(const float4*)(b2 + mt * 16 + kg * 4);
  }
  const float b1j = b1[w * 16 + ln16];
  {
    unsigned* cw = (unsigned*)(S + OFF_CW);
    for (int i = t; i < 640; i += 256) cw[i] = 0;
  }
  __syncthreads();
  if (t < 128) {
    unsigned* cw = (unsigned*)(S + OFF_CW);
    atomicAdd(&cw[ed * 8 + (es >> 2)], 1u << ((es & 3) * 8));
    atomicAdd(&cw[256 + ed], 1u);
    atomicAdd(&cw[288 + es], 1u);
  }
  #pragma unroll
  for (int i = 0; i < 8; i++) {
    f32x4 tmp = {ev[i].x, ev[i].y, ev[i].z, ev[i].w};
    *(bf16x4*)(S + OFF_EB + (w * 8 + i) * 528 + l * 8) = cvt4(tmp);
  }
  if (NG > 1) {
    const int gid = gid0 + 1;
    const float* Eg = ((gid >> 12) ? obj : subj) + (size_t)(gid & (BGR - 1)) * 32 * DIM;
    #pragma unroll
    for (int i = 0; i < 8; i++)
      ev[i] = *(const float4*)(Eg + (w * 8 + i) * 256 + l * 4);
    if (t < 128) {
      es = (((gid >> 12) ? osrc : ssrc))[(gid & (BGR - 1)) * 128 + t] & 31;
      ed = (((gid >> 12) ? odst : sdst))[(gid & (BGR - 1)) * 128 + t] & 31;
    }
  }

  for (int g = 0; g < NG; g++) {
    unsigned* cwc = (unsigned*)(S + OFF_CW + (g & 1) * 1280);
    unsigned* cwn = (unsigned*)(S + OFF_CW + ((g + 1) & 1) * 1280);

    lds_barrier();                                 // B1: Ebf(g), cw[g&1] ready

    // ---- P1: gemm0 -> YT; zero cw[nxt] ----
    {
      f32x4 a00 = {0,0,0,0}, a01 = {0,0,0,0}, a10 = {0,0,0,0}, a11 = {0,0,0,0};
      const unsigned char* ea = S + OFF_EB + ln16 * 528 + kg * 16;
      #pragma unroll
      for (int ks = 0; ks < 8; ks++) {
        bf16x8 A0 = *(const bf16x8*)(ea + ks * 64);
        bf16x8 A1 = *(const bf16x8*)(ea + 16 * 528 + ks * 64);
        a00 = __builtin_amdgcn_mfma_f32_16x16x32_bf16(A0, B0[ks], a00, 0, 0, 0);
        a01 = __builtin_amdgcn_mfma_f32_16x16x32_bf16(A0, B1[ks], a01, 0, 0, 0);
        a10 = __builtin_amdgcn_mfma_f32_16x16x32_bf16(A1, B0[ks], a10, 0, 0, 0);
        a11 = __builtin_amdgcn_mfma_f32_16x16x32_bf16(A1, B1[ks], a11, 0, 0, 0);
      }
      *(bf16x4*)(S + OFF_YT + ((2 * w) * 16 + ln16) * 80 + (kg * 4) * 2)          = cvt4(a00);
      *(bf16x4*)(S + OFF_YT + ((2 * w + 1) * 16 + ln16) * 80 + (kg * 4) * 2)      = cvt4(a01);
      *(bf16x4*)(S + OFF_YT + ((2 * w) * 16 + ln16) * 80 + (16 + kg * 4) * 2)     = cvt4(a10);
      *(bf16x4*)(S + OFF_YT + ((2 * w + 1) * 16 + ln16) * 80 + (16 + kg * 4) * 2) = cvt4(a11);
      if (g + 1 < NG) for (int i = t; i < 320; i += 256) cwn[i] = 0;
    }
    lds_barrier();                                 // B2: YT ready; Ebf dead

    // ---- STAGE (off critical path): cvt(g+1), count(g+1), issue(g+2) ----
    if (g + 1 < NG) {
      #pragma unroll
      for (int i = 0; i < 8; i++) {
        f32x4 tmp = {ev[i].x, ev[i].y, ev[i].z, ev[i].w};
        *(bf16x4*)(S + OFF_EB + (w * 8 + i) * 528 + l * 8) = cvt4(tmp);
      }
      if (t < 128) {
        atomicAdd(&cwn[ed * 8 + (es >> 2)], 1u << ((es & 3) * 8));
        atomicAdd(&cwn[256 + ed], 1u);
        atomicAdd(&cwn[288 + es], 1u);
      }
      if (g + 2 < NG) {
        const int ngid = gid0 + g + 2, ngg = ngid & (BGR - 1);
        const float* Eg = ((ngid >> 12) ? obj : subj) + (size_t)ngg * 32 * DIM;
        #pragma unroll
        for (int i = 0; i < 8; i++)
          ev[i] = *(const float4*)(Eg + (w * 8 + i) * 256 + l * 4);
        if (t < 128) {
          es = (((ngid >> 12) ? osrc : ssrc))[ngg * 128 + t] & 31;
          ed = (((ngid >> 12) ? odst : sdst))[ngg * 128 + t] & 31;
        }
      }
    }

    // ---- P2: M fragments + step1 -> H1T ----
    bf16x8 m1f[2], m2f[2];
    #pragma unroll
    for (int hf = 0; hf < 2; hf++) {
      const int r = hf * 16 + ln16;
      const float fi = 1.0f / fmaxf((float)cwc[256 + r], 1.0f);
      const float fo = 1.0f / fmaxf((float)cwc[288 + r], 1.0f);
      const unsigned w0 = cwc[r * 8 + kg * 2], w1 = cwc[r * 8 + kg * 2 + 1];
      bf16x8 a, b;
      #pragma unroll
      for (int q = 0; q < 4; q++) {
        a[q]     = (__bf16)((float)((w0 >> (q * 8)) & 255u) * fi);
        a[4 + q] = (__bf16)((float)((w1 >> (q * 8)) & 255u) * fi);
      }
      #pragma unroll
      for (int q = 0; q < 8; q++) {
        const unsigned wq = cwc[(kg * 8 + q) * 8 + (r >> 2)];
        b[q] = (__bf16)((float)((wq >> ((r & 3) * 8)) & 255u) * fo);
      }
      m1f[hf] = a; m2f[hf] = b;
    }
    {
      bf16x8 Byo = *(const bf16x8*)(S + OFF_YT + (w * 16 + ln16) * 80 + kg * 16);
      bf16x8 Byi = *(const bf16x8*)(S + OFF_YT + (64 + w * 16 + ln16) * 80 + kg * 16);
      #pragma unroll
      for (int mt = 0; mt < 2; mt++) {
        f32x4 z = {0.f, 0.f, 0.f, 0.f};
        f32x4 c = __builtin_amdgcn_mfma_f32_16x16x32_bf16(m1f[mt], Byo, z, 0, 0, 0);
        c = __builtin_amdgcn_mfma_f32_16x16x32_bf16(m2f[mt], Byi, c, 0, 0, 0);
        f32x4 hv = { fmaxf(c[0] + b1j, 0.f), fmaxf(c[1] + b1j, 0.f),
                     fmaxf(c[2] + b1j, 0.f), fmaxf(c[3] + b1j, 0.f) };
        *(bf16x4*)(S + OFF_H1 + (w * 16 + ln16) * 72 + (mt * 16 + kg * 4) * 2) = cvt4(hv);
      }
    }
    // no barrier: P3 reads only this wave's H1T rows (program order)

    // ---- P3: step2 -> A2 ----
    {
      bf16x8 Af = *(const bf16x8*)(S + OFF_H1 + (w * 16 + ln16) * 72 + kg * 16);
      #pragma unroll
      for (int hf = 0; hf < 2; hf++)
        #pragma unroll
        for (int ntd = 0; ntd < 2; ntd++) {
          f32x4 z = {0.f, 0.f, 0.f, 0.f};
          f32x4 c = __builtin_amdgcn_mfma_f32_16x16x32_bf16(
              Af, hf ? m2f[ntd] : m1f[ntd], z, 0, 0, 0);
          *(bf16x4*)(S + OFF_A2 + (ntd * 16 + ln16) * 272 + hf * 128 + w * 32 + kg * 8) = cvt4(c);
        }
    }
    lds_barrier();                                 // B4: A2 ready

    // ---- P4: step3 (register W2) + fused mean readout ----
    {
      bf16x8 BF[2][4];
      #pragma unroll
      for (int ntd = 0; ntd < 2; ntd++)
        #pragma unroll
        for (int ks = 0; ks < 4; ks++)
          BF[ntd][ks] = *(const bf16x8*)(S + OFF_A2 + (ntd * 16 + ln16) * 272 + ks * 64 + kg * 16);
      #pragma unroll
      for (int q = 0; q < 4; q++) {
        const int mt = w * 4 + q;
        f32x4 a0 = {0.f, 0.f, 0.f, 0.f}, a1 = {0.f, 0.f, 0.f, 0.f};
        #pragma unroll
        for (int ks = 0; ks < 4; ks++) {
          a0 = __builtin_amdgcn_mfma_f32_16x16x32_bf16(AW[q][ks], BF[0][ks], a0, 0, 0, 0);
          a1 = __builtin_amdgcn_mfma_f32_16x16x32_bf16(AW[q][ks], BF[1][ks], a1, 0, 0, 0);
        }
        float v0 = fmaxf(a0[0] + b2v[q].x, 0.f) + fmaxf(a1[0] + b2v[q].x, 0.f);
        float v1 = fmaxf(a0[1] + b2v[q].y, 0.f) + fmaxf(a1[1] + b2v[q].y, 0.f);
        float v2 = fmaxf(a0[2] + b2v[q].z, 0.f) + fmaxf(a1[2] + b2v[q].z, 0.f);
        float v3 = fmaxf(a0[3] + b2v[q].w, 0.f) + fmaxf(a1[3] + b2v[q].w, 0.f);
        #pragma unroll
        for (int d = 1; d < 16; d <<= 1) {
          v0 += __shfl_xor(v0, d); v1 += __shfl_xor(v1, d);
          v2 += __shfl_xor(v2, d); v3 += __shfl_xor(v3, d);
        }
        if (ln16 == 0) {
          float4 o = { v0 * 0.03125f, v1 * 0.03125f, v2 * 0.03125f, v3 * 0.03125f };
          *(float4*)(gout + (size_t)(gid0 + g) * DIM + mt * 16 + kg * 4) = o;
        }
      }
    }
  }
}

// ---------------------------------------------------------------------------
// Distances: pos = ||h+r-t||, neg = ||h[ch]+r-t[ct]||. One wave per triple.
// ---------------------------------------------------------------------------
__global__ __launch_bounds__(256) void dist_kernel(
    const float* __restrict__ hemb, const float* __restrict__ temb,
    const float* __restrict__ remb, const int* __restrict__ chx,
    const int* __restrict__ ctx, float* __restrict__ out)
{
  const int t = threadIdx.x;
  const int w = t >> 6, l = t & 63;
  const int b = (blockIdx.x << 2) + w;
  float4 h4 = *(const float4*)(hemb + (size_t)b * DIM + (l << 2));
  float4 r4 = *(const float4*)(remb + (size_t)b * DIM + (l << 2));
  float4 t4 = *(const float4*)(temb + (size_t)b * DIM + (l << 2));
  int hb = chx[b], tb = ctx[b];
  float4 hn = *(const float4*)(hemb + (size_t)hb * DIM + (l << 2));
  float4 tn = *(const float4*)(temb + (size_t)tb * DIM + (l << 2));
  float x0 = h4.x + r4.x - t4.x, x1 = h4.y + r4.y - t4.y;
  float x2 = h4.z + r4.z - t4.z, x3 = h4.w + r4.w - t4.w;
  float dp = x0*x0 + x1*x1 + x2*x2 + x3*x3;
  float y0 = hn.x + r4.x - tn.x, y1 = hn.y + r4.y - tn.y;
  float y2 = hn.z + r4.z - tn.z, y3 = hn.w + r4.w - tn.w;
  float dn = y0*y0 + y1*y1 + y2*y2 + y3*y3;
  #pragma unroll
  for (int off = 32; off >= 1; off >>= 1) {
    dp += __shfl_down(dp, off);
    dn += __shfl_down(dn, off);
  }
  if (l == 0) {
    out[b] = sqrtf(dp);
    out[BGR + b] = sqrtf(dn);
  }
}

extern "C" void kernel_launch(void* const* d_in, const int* in_sizes, int n_in,
                              void* d_out, int out_size, void* d_ws, size_t ws_size,
                              hipStream_t stream) {
  const float* subj_embs = (const float*)d_in[0];
  const float* obj_embs  = (const float*)d_in[1];
  const float* rel_tok   = (const float*)d_in[2];
  const int* subj_src = (const int*)d_in[3];
  const int* subj_dst = (const int*)d_in[4];
  const int* obj_src  = (const int*)d_in[5];
  const int* obj_dst  = (const int*)d_in[6];
  // d_in[7] = node_graph_ids (implicit by construction)
  const int* chx = (const int*)d_in[8];
  const int* ctx = (const int*)d_in[9];
  const float* WO1 = (const float*)d_in[10];
  const float* bO1 = (const float*)d_in[11];
  const float* WI1 = (const float*)d_in[12];
  const float* bI1 = (const float*)d_in[13];
  const float* WO2 = (const float*)d_in[14];
  const float* bO2 = (const float*)d_in[15];
  const float* WI2 = (const float*)d_in[16];
  const float* bI2 = (const float*)d_in[17];
  const float* relW = (const float*)d_in[18];
  const float* relb = (const float*)d_in[19];

  float* g_embs = (float*)d_ws;                           // [8192,256] f32 = 8 MB
  float* r_embs = g_embs + (size_t)2 * BGR * DIM;         // [4096,256] f32 = 4 MB
  unsigned short* W1b = (unsigned short*)((char*)d_ws + 12582912);  // 64 KB
  unsigned short* W2b = W1b + 32768;                                // 64 KB
  float* b1 = (float*)((char*)d_ws + 12713984);                     // 256 B
  float* b2 = b1 + 64;                                              // 1 KB
  float* out = (float*)d_out;                             // [8192]: pos | neg

  wcvt_kernel<<<128, 256, 0, stream>>>(WO1, WI1, WO2, WI2, bO1, bI1, bO2, bI2,
                                       W1b, W2b, b1, b2);
  mega_kernel<<<NFUSED + 256, 256, 0, stream>>>(
      subj_embs, obj_embs, subj_src, subj_dst, obj_src, obj_dst,
      W1b, W2b, b1, b2, rel_tok, relW, relb, g_embs, r_embs);
  dist_kernel<<<BGR / 4, 256, 0, stream>>>(
      g_embs, g_embs + (size_t)BGR * DIM, r_embs, chx, ctx, out);
}